// Round 9
// baseline (508.621 us; speedup 1.0000x reference)
//
#include <hip/hip_runtime.h>
#include <hip/hip_bf16.h>
#include <stdint.h>

// Problem constants
#define NN   1000000      // NUM_NODES
#define DD   128          // MEM_DIM == MSG_DIM
#define BT   262144       // batch B
#define TR   64           // rows per LDS tile (4 MFMA sub-tiles)
#define RPB  512          // batch rows per GRU block
#define NT   (RPB / TR)   // 8 tiles per block
#define GRUB (BT / RPB)   // 512 GRU blocks
#define WINBIT (1 << 30)

typedef __attribute__((ext_vector_type(8))) short bf16x8;  // 8 bf16 in 4 VGPRs
typedef __attribute__((ext_vector_type(4))) float f32x4;

// float pair -> packed bf16x2 via v_cvt_pk_bf16_f32 (compiler-emitted)
__device__ __forceinline__ uint32_t f2bf2(float lo, float hi) {
    __hip_bfloat162 b = __float22bfloat162_rn(make_float2(lo, hi));
    uint32_t u; __builtin_memcpy(&u, &b, 4); return u;
}
__device__ __forceinline__ bf16x8 cvt8(float4 a, float4 b) {
    union { bf16x8 v; uint32_t u[4]; } r;
    r.u[0] = f2bf2(a.x, a.y);
    r.u[1] = f2bf2(a.z, a.w);
    r.u[2] = f2bf2(b.x, b.y);
    r.u[3] = f2bf2(b.z, b.w);
    return r.v;
}
__device__ __forceinline__ float bf2f(unsigned short s) {
    union { uint32_t u; float f; } c; c.u = ((uint32_t)s) << 16;
    return c.f;
}
__device__ __forceinline__ float fastrcp(float x) {
    return __builtin_amdgcn_rcpf(x);
}
__device__ __forceinline__ float sigmoid_f(float x) {
    return fastrcp(1.0f + __expf(-x));
}
__device__ __forceinline__ float tanh_f(float x) {
    return fmaf(2.0f, fastrcp(1.0f + __expf(-2.0f * x)), -1.0f);
}

// ---------------------------------------------------------------------------
// winner[] = -1
__global__ __launch_bounds__(256) void k_init(int4* __restrict__ winner) {
    int i = blockIdx.x * 256 + threadIdx.x;
    if (i < NN / 4) winner[i] = make_int4(-1, -1, -1, -1);
}

// last-occurrence-wins winner per node
__global__ __launch_bounds__(256) void k_winner(const int* __restrict__ node_ids,
                                                int* __restrict__ winner) {
    int i = blockIdx.x * 256 + threadIdx.x;
    if (i < BT) atomicMax(&winner[node_ids[i]], i);
}

// ---------------------------------------------------------------------------
// copy memory rows not owned by a winner; write last_update for all nodes.
__global__ __launch_bounds__(256) void k_copy(const float4* __restrict__ mem_in,
                                              const float* __restrict__ lu_in,
                                              const float* __restrict__ ts,
                                              const int* __restrict__ winner,
                                              float4* __restrict__ mem_out,
                                              float* __restrict__ lu_out) {
    const long NV4 = (long)NN * 32;        // 32 float4 per row
    const long TOTAL = NV4 + NN;
    long stride = (long)gridDim.x * 256;
    for (long i = blockIdx.x * 256L + threadIdx.x; i < TOTAL; i += stride) {
        if (i < NV4) {
            int node = (int)(i >> 5);
            if (winner[node] < 0) mem_out[i] = mem_in[i];
        } else {
            int v = (int)(i - NV4);
            int w = winner[v];
            lu_out[v] = (w >= 0) ? ts[w] : lu_in[v];
        }
    }
}

// ---------------------------------------------------------------------------
// Fused gather + GRU (bf16 MFMA) + gated scatter.
// 512 thr = 8 waves; wave w owns output cols [16w,16w+16), all 24 weight
// B-fragments register-resident. 8 tiles of 64 rows, double-buffered
// XOR-swizzled bf16 LDS, one lgkm-only barrier per tile.
// PIPELINE (this round): h-gathers use TWO ping-ponged register sets so
// GLOADH(t+1) is issued as the FIRST op of each tile — before the stage
// waits on set(t) — keeping a full tile of gathers in flight at all times.
// x reloads issue immediately after x-cvt (WAR on just-read regs).
// mfma_f32_16x16x32_bf16: A[r][k]: r=lane&15, k=8*(lane>>4)+e
//                         B[k][n]: n=lane&15, same k
//                         D[r][c]: c=lane&15, r=4*(lane>>4)+q
__global__ __launch_bounds__(512, 4) void k_gru(const float* __restrict__ memory,
                                                const float* __restrict__ messages,
                                                const float* __restrict__ W_ih,
                                                const float* __restrict__ W_hh,
                                                const float* __restrict__ b_ih,
                                                const float* __restrict__ b_hh,
                                                const int* __restrict__ node_ids,
                                                const int* __restrict__ winner,
                                                float* __restrict__ out_mem) {
    __shared__ unsigned short x_lds[2][TR * DD];   // 2 x 16 KB, swizzled
    __shared__ unsigned short h_lds[2][TR * DD];   // 2 x 16 KB, swizzled
    __shared__ int s_nid[RPB];                     // nid | (win << 30)

    const int tid = threadIdx.x;
    const int rowBase = blockIdx.x * RPB;

    for (int i = tid; i < RPB; i += 512) {
        int brow = rowBase + i;
        int nid = node_ids[brow];
        s_nid[i] = nid | ((winner[nid] == brow) ? WINBIT : 0);
    }
    __syncthreads();

    const int lane  = tid & 63;
    const int wave  = tid >> 6;
    const int l15   = lane & 15;
    const int khalf = lane >> 4;            // 0..3
    const int jcol  = wave * 16 + l15;      // this lane's output column

    // weight fragments (fp32 -> bf16 via cvt_pk), register-resident
    bf16x8 wf[6][4];
#pragma unroll
    for (int g = 0; g < 3; ++g) {
#pragma unroll
        for (int ks = 0; ks < 4; ++ks) {
            const float* p = W_ih + (size_t)(g * 128 + jcol) * DD + ks * 32 + khalf * 8;
            wf[g][ks] = cvt8(*(const float4*)p, *(const float4*)(p + 4));
            const float* q = W_hh + (size_t)(g * 128 + jcol) * DD + ks * 32 + khalf * 8;
            wf[3 + g][ks] = cvt8(*(const float4*)q, *(const float4*)(q + 4));
        }
    }
    // biases folded into accumulator init
    const float br  = b_ih[jcol] + b_hh[jcol];
    const float bz  = b_ih[128 + jcol] + b_hh[128 + jcol];
    const float bin = b_ih[256 + jcol];
    const float bhn = b_hh[256 + jcol];

    // staging geometry: half-tile of 32 rows; thread -> (row sr, 8-col sc8)
    const int sr  = tid >> 4;               // 0..31
    const int sc8 = (tid & 15) * 8;         // 0..120
    const int swz = (sc8 * 2) ^ ((sr & 7) << 4);
    const int offH0 = sr * 256 + swz;
    const int offH1 = (32 + sr) * 256 + swz;

#define GLOADX(t)                                                               \
    {                                                                           \
        int r_ = (t) * TR + sr;                                                 \
        const float* xp0_ = messages + (size_t)(rowBase + r_) * DD + sc8;       \
        const float* xp1_ = messages + (size_t)(rowBase + r_ + 32) * DD + sc8;  \
        xA0 = ((const float4*)xp0_)[0]; xA1 = ((const float4*)xp0_)[1];         \
        xB0 = ((const float4*)xp1_)[0]; xB1 = ((const float4*)xp1_)[1];         \
    }
#define GLOADH(H0, H1, H2, H3, t)                                               \
    {                                                                           \
        int r_ = (t) * TR + sr;                                                 \
        const float* hp0_ = memory + (size_t)(s_nid[r_] & (WINBIT - 1)) * DD + sc8; \
        const float* hp1_ = memory + (size_t)(s_nid[r_ + 32] & (WINBIT - 1)) * DD + sc8; \
        H0 = ((const float4*)hp0_)[0]; H1 = ((const float4*)hp0_)[1];           \
        H2 = ((const float4*)hp1_)[0]; H3 = ((const float4*)hp1_)[1];           \
    }

    // x: single set; h: two ping-ponged sets (P, Q)
    float4 xA0, xA1, xB0, xB1;
    float4 hP0, hP1, hP2, hP3, hQ0, hQ1, hQ2, hQ3;

    GLOADH(hP0, hP1, hP2, hP3, 0);   // h tile 0 -> P
    GLOADX(0);                       // x tile 0

#define BODY(t, HC0, HC1, HC2, HC3, HN0, HN1, HN2, HN3)                         \
    {                                                                           \
        const int buf = (t) & 1;                                                \
        char* xb = (char*)(&x_lds[buf][0]);                                     \
        char* hb = (char*)(&h_lds[buf][0]);                                     \
        /* 1: issue next h-gathers FIRST (into the other set) */                \
        if ((t) + 1 < NT) GLOADH(HN0, HN1, HN2, HN3, (t) + 1);                  \
        /* 2: stage x(t) (waits x loads), then immediately reload x(t+1) */     \
        *(bf16x8*)(xb + offH0) = cvt8(xA0, xA1);                                \
        *(bf16x8*)(xb + offH1) = cvt8(xB0, xB1);                                \
        if ((t) + 1 < NT) GLOADX((t) + 1);                                      \
        /* 3: stage h(t) from current set */                                    \
        *(bf16x8*)(hb + offH0) = cvt8(HC0, HC1);                                \
        *(bf16x8*)(hb + offH1) = cvt8(HC2, HC3);                                \
        /* 4: LDS-visible barrier that does NOT drain vmcnt */                  \
        asm volatile("s_waitcnt lgkmcnt(0)" ::: "memory");                      \
        __builtin_amdgcn_sched_barrier(0);                                      \
        __builtin_amdgcn_s_barrier();                                           \
        __builtin_amdgcn_sched_barrier(0);                                      \
        /* 5: compute four 16-row sub-tiles */                                  \
        _Pragma("unroll")                                                       \
        for (int sub = 0; sub < 4; ++sub) {                                     \
            const int arow = sub * 16 + l15;                                    \
            const char* xr = (const char*)(&x_lds[buf][0]) + arow * 256;        \
            const char* hr = (const char*)(&h_lds[buf][0]) + arow * 256;        \
            const int aswz = (arow & 7) << 4;                                   \
            bf16x8 ax[4], ah[4];                                                \
            _Pragma("unroll")                                                   \
            for (int ks = 0; ks < 4; ++ks) {                                    \
                const int cb = (ks * 64 + khalf * 16) ^ aswz;                   \
                ax[ks] = *(const bf16x8*)(xr + cb);                             \
                ah[ks] = *(const bf16x8*)(hr + cb);                             \
            }                                                                   \
            f32x4 a_r  = {br,  br,  br,  br};                                   \
            f32x4 a_z  = {bz,  bz,  bz,  bz};                                   \
            f32x4 a_in = {bin, bin, bin, bin};                                  \
            f32x4 a_hn = {bhn, bhn, bhn, bhn};                                  \
            _Pragma("unroll")                                                   \
            for (int ks = 0; ks < 4; ++ks) {                                    \
                a_r  = __builtin_amdgcn_mfma_f32_16x16x32_bf16(ax[ks], wf[0][ks], a_r,  0, 0, 0); \
                a_r  = __builtin_amdgcn_mfma_f32_16x16x32_bf16(ah[ks], wf[3][ks], a_r,  0, 0, 0); \
                a_z  = __builtin_amdgcn_mfma_f32_16x16x32_bf16(ax[ks], wf[1][ks], a_z,  0, 0, 0); \
                a_z  = __builtin_amdgcn_mfma_f32_16x16x32_bf16(ah[ks], wf[4][ks], a_z,  0, 0, 0); \
                a_in = __builtin_amdgcn_mfma_f32_16x16x32_bf16(ax[ks], wf[2][ks], a_in, 0, 0, 0); \
                a_hn = __builtin_amdgcn_mfma_f32_16x16x32_bf16(ah[ks], wf[5][ks], a_hn, 0, 0, 0); \
            }                                                                   \
            _Pragma("unroll")                                                   \
            for (int q = 0; q < 4; ++q) {                                       \
                const int rl = sub * 16 + khalf * 4 + q;                        \
                const int tr = (t) * TR + rl;                                   \
                float rg = sigmoid_f(a_r[q]);                                   \
                float zg = sigmoid_f(a_z[q]);                                   \
                float ng = tanh_f(a_in[q] + rg * a_hn[q]);                      \
                unsigned short hu = *(const unsigned short*)(                   \
                    (const char*)(&h_lds[buf][0]) + rl * 256 + ((jcol * 2) ^ ((rl & 7) << 4))); \
                float h = bf2f(hu);                                             \
                float hnew = fmaf(zg, h - ng, ng);                              \
                int v = s_nid[tr];                                              \
                if (v & WINBIT)                                                 \
                    out_mem[(size_t)(v & (WINBIT - 1)) * DD + jcol] = hnew;     \
            }                                                                   \
        }                                                                       \
    }

#pragma unroll 1
    for (int tp = 0; tp < NT; tp += 2) {
        BODY(tp,     hP0, hP1, hP2, hP3, hQ0, hQ1, hQ2, hQ3);
        BODY(tp + 1, hQ0, hQ1, hQ2, hQ3, hP0, hP1, hP2, hP3);
    }
#undef BODY
#undef GLOADX
#undef GLOADH
}

// ---------------------------------------------------------------------------
extern "C" void kernel_launch(void* const* d_in, const int* in_sizes, int n_in,
                              void* d_out, int out_size, void* d_ws, size_t ws_size,
                              hipStream_t stream) {
    const float* memory      = (const float*)d_in[0];
    const float* last_update = (const float*)d_in[1];
    const float* messages    = (const float*)d_in[2];
    const float* timestamps  = (const float*)d_in[3];
    const float* W_ih        = (const float*)d_in[4];
    const float* W_hh        = (const float*)d_in[5];
    const float* b_ih        = (const float*)d_in[6];
    const float* b_hh        = (const float*)d_in[7];
    const int*   node_ids    = (const int*)d_in[8];

    float* out_mem = (float*)d_out;
    float* out_lu  = out_mem + (size_t)NN * DD;

    int* winner = (int*)d_ws;

    k_init<<<(NN / 4 + 255) / 256, 256, 0, stream>>>((int4*)winner);
    k_winner<<<BT / 256, 256, 0, stream>>>(node_ids, winner);
    k_copy<<<4096, 256, 0, stream>>>((const float4*)memory, last_update, timestamps,
                                     winner, (float4*)out_mem, out_lu);
    k_gru<<<GRUB, 512, 0, stream>>>(memory, messages, W_ih, W_hh, b_ih, b_hh,
                                    node_ids, winner, out_mem);
}

// Round 10
// 281.916 us; speedup vs baseline: 1.8042x; 1.8042x over previous
//
#include <hip/hip_runtime.h>
#include <hip/hip_bf16.h>
#include <stdint.h>

// Problem constants
#define NN   1000000      // NUM_NODES
#define DD   128          // MEM_DIM == MSG_DIM
#define BT   262144       // batch B
#define TR   64           // rows per LDS tile (4 MFMA sub-tiles)
#define RPB  512          // batch rows per GRU block
#define NT   (RPB / TR)   // 8 tiles per block
#define GRUB (BT / RPB)   // 512 GRU blocks
#define WINBIT (1 << 30)

typedef __attribute__((ext_vector_type(8))) short bf16x8;  // 8 bf16 in 4 VGPRs
typedef __attribute__((ext_vector_type(4))) float f32x4;

// float pair -> packed bf16x2 via v_cvt_pk_bf16_f32 (compiler-emitted)
__device__ __forceinline__ uint32_t f2bf2(float lo, float hi) {
    __hip_bfloat162 b = __float22bfloat162_rn(make_float2(lo, hi));
    uint32_t u; __builtin_memcpy(&u, &b, 4); return u;
}
__device__ __forceinline__ bf16x8 cvt8(float4 a, float4 b) {
    union { bf16x8 v; uint32_t u[4]; } r;
    r.u[0] = f2bf2(a.x, a.y);
    r.u[1] = f2bf2(a.z, a.w);
    r.u[2] = f2bf2(b.x, b.y);
    r.u[3] = f2bf2(b.z, b.w);
    return r.v;
}
__device__ __forceinline__ float bf2f(unsigned short s) {
    union { uint32_t u; float f; } c; c.u = ((uint32_t)s) << 16;
    return c.f;
}
__device__ __forceinline__ float fastrcp(float x) {
    return __builtin_amdgcn_rcpf(x);
}
__device__ __forceinline__ float sigmoid_f(float x) {
    return fastrcp(1.0f + __expf(-x));
}
__device__ __forceinline__ float tanh_f(float x) {
    return fmaf(2.0f, fastrcp(1.0f + __expf(-2.0f * x)), -1.0f);
}

// ---------------------------------------------------------------------------
// winner[] = -1
__global__ __launch_bounds__(256) void k_init(int4* __restrict__ winner) {
    int i = blockIdx.x * 256 + threadIdx.x;
    if (i < NN / 4) winner[i] = make_int4(-1, -1, -1, -1);
}

// last-occurrence-wins winner per node
__global__ __launch_bounds__(256) void k_winner(const int* __restrict__ node_ids,
                                                int* __restrict__ winner) {
    int i = blockIdx.x * 256 + threadIdx.x;
    if (i < BT) atomicMax(&winner[node_ids[i]], i);
}

// ---------------------------------------------------------------------------
// copy memory rows not owned by a winner; write last_update for all nodes.
__global__ __launch_bounds__(256) void k_copy(const float4* __restrict__ mem_in,
                                              const float* __restrict__ lu_in,
                                              const float* __restrict__ ts,
                                              const int* __restrict__ winner,
                                              float4* __restrict__ mem_out,
                                              float* __restrict__ lu_out) {
    const long NV4 = (long)NN * 32;        // 32 float4 per row
    const long TOTAL = NV4 + NN;
    long stride = (long)gridDim.x * 256;
    for (long i = blockIdx.x * 256L + threadIdx.x; i < TOTAL; i += stride) {
        if (i < NV4) {
            int node = (int)(i >> 5);
            if (winner[node] < 0) mem_out[i] = mem_in[i];
        } else {
            int v = (int)(i - NV4);
            int w = winner[v];
            lu_out[v] = (w >= 0) ? ts[w] : lu_in[v];
        }
    }
}

// ---------------------------------------------------------------------------
// Fused gather + GRU (bf16 MFMA) + gated scatter.
// 512 thr = 8 waves; wave w owns output cols [16w,16w+16), all 24 weight
// B-fragments register-resident. 8 tiles of 64 rows, double-buffered
// XOR-swizzled bf16 LDS, one lgkm-only barrier per tile.
// Depth-2 h-gather pipeline: two ping-ponged register sets; GLOADH(t+1)
// issues as the FIRST op of tile t (before any waits), so each h-gather has
// a full tile iteration (compute+barrier) to land. x reloads issue right
// after x's cvt (WAR on just-read regs) and ride across the barrier.
// launch_bounds (512,1): VGPR UNCAPPED — (512,2)'s 128 cap forced spills
// (round-8 VGPR=128 exact) and (512,4)'s 64 cap was catastrophic (r7/r9).
// mfma_f32_16x16x32_bf16: A[r][k]: r=lane&15, k=8*(lane>>4)+e
//                         B[k][n]: n=lane&15, same k
//                         D[r][c]: c=lane&15, r=4*(lane>>4)+q
__global__ __launch_bounds__(512, 1) void k_gru(const float* __restrict__ memory,
                                                const float* __restrict__ messages,
                                                const float* __restrict__ W_ih,
                                                const float* __restrict__ W_hh,
                                                const float* __restrict__ b_ih,
                                                const float* __restrict__ b_hh,
                                                const int* __restrict__ node_ids,
                                                const int* __restrict__ winner,
                                                float* __restrict__ out_mem) {
    __shared__ unsigned short x_lds[2][TR * DD];   // 2 x 16 KB, swizzled
    __shared__ unsigned short h_lds[2][TR * DD];   // 2 x 16 KB, swizzled
    __shared__ int s_nid[RPB];                     // nid | (win << 30)

    const int tid = threadIdx.x;
    const int rowBase = blockIdx.x * RPB;

    for (int i = tid; i < RPB; i += 512) {
        int brow = rowBase + i;
        int nid = node_ids[brow];
        s_nid[i] = nid | ((winner[nid] == brow) ? WINBIT : 0);
    }
    __syncthreads();

    const int lane  = tid & 63;
    const int wave  = tid >> 6;
    const int l15   = lane & 15;
    const int khalf = lane >> 4;            // 0..3
    const int jcol  = wave * 16 + l15;      // this lane's output column

    // weight fragments (fp32 -> bf16 via cvt_pk), register-resident
    bf16x8 wf[6][4];
#pragma unroll
    for (int g = 0; g < 3; ++g) {
#pragma unroll
        for (int ks = 0; ks < 4; ++ks) {
            const float* p = W_ih + (size_t)(g * 128 + jcol) * DD + ks * 32 + khalf * 8;
            wf[g][ks] = cvt8(*(const float4*)p, *(const float4*)(p + 4));
            const float* q = W_hh + (size_t)(g * 128 + jcol) * DD + ks * 32 + khalf * 8;
            wf[3 + g][ks] = cvt8(*(const float4*)q, *(const float4*)(q + 4));
        }
    }
    // biases folded into accumulator init
    const float br  = b_ih[jcol] + b_hh[jcol];
    const float bz  = b_ih[128 + jcol] + b_hh[128 + jcol];
    const float bin = b_ih[256 + jcol];
    const float bhn = b_hh[256 + jcol];

    // staging geometry: half-tile of 32 rows; thread -> (row sr, 8-col sc8)
    const int sr  = tid >> 4;               // 0..31
    const int sc8 = (tid & 15) * 8;         // 0..120
    const int swz = (sc8 * 2) ^ ((sr & 7) << 4);
    const int offH0 = sr * 256 + swz;
    const int offH1 = (32 + sr) * 256 + swz;

#define GLOADX(t)                                                               \
    {                                                                           \
        int r_ = (t) * TR + sr;                                                 \
        const float* xp0_ = messages + (size_t)(rowBase + r_) * DD + sc8;       \
        const float* xp1_ = messages + (size_t)(rowBase + r_ + 32) * DD + sc8;  \
        xA0 = ((const float4*)xp0_)[0]; xA1 = ((const float4*)xp0_)[1];         \
        xB0 = ((const float4*)xp1_)[0]; xB1 = ((const float4*)xp1_)[1];         \
    }
#define GLOADH(H0, H1, H2, H3, t)                                               \
    {                                                                           \
        int r_ = (t) * TR + sr;                                                 \
        const float* hp0_ = memory + (size_t)(s_nid[r_] & (WINBIT - 1)) * DD + sc8; \
        const float* hp1_ = memory + (size_t)(s_nid[r_ + 32] & (WINBIT - 1)) * DD + sc8; \
        H0 = ((const float4*)hp0_)[0]; H1 = ((const float4*)hp0_)[1];           \
        H2 = ((const float4*)hp1_)[0]; H3 = ((const float4*)hp1_)[1];           \
    }

    // x: single set; h: two ping-ponged sets (P, Q)
    float4 xA0, xA1, xB0, xB1;
    float4 hP0, hP1, hP2, hP3, hQ0, hQ1, hQ2, hQ3;

    GLOADH(hP0, hP1, hP2, hP3, 0);   // h tile 0 -> P
    GLOADX(0);                       // x tile 0

#define BODY(t, HC0, HC1, HC2, HC3, HN0, HN1, HN2, HN3)                         \
    {                                                                           \
        const int buf = (t) & 1;                                                \
        char* xb = (char*)(&x_lds[buf][0]);                                     \
        char* hb = (char*)(&h_lds[buf][0]);                                     \
        /* 1: issue next h-gathers FIRST (into the other set) */                \
        if ((t) + 1 < NT) GLOADH(HN0, HN1, HN2, HN3, (t) + 1);                  \
        /* 2: stage x(t) (waits x loads), then immediately reload x(t+1) */     \
        *(bf16x8*)(xb + offH0) = cvt8(xA0, xA1);                                \
        *(bf16x8*)(xb + offH1) = cvt8(xB0, xB1);                                \
        if ((t) + 1 < NT) GLOADX((t) + 1);                                      \
        /* 3: stage h(t) from current set */                                    \
        *(bf16x8*)(hb + offH0) = cvt8(HC0, HC1);                                \
        *(bf16x8*)(hb + offH1) = cvt8(HC2, HC3);                                \
        /* 4: LDS-visible barrier that does NOT drain vmcnt */                  \
        asm volatile("s_waitcnt lgkmcnt(0)" ::: "memory");                      \
        __builtin_amdgcn_sched_barrier(0);                                      \
        __builtin_amdgcn_s_barrier();                                           \
        __builtin_amdgcn_sched_barrier(0);                                      \
        /* 5: compute four 16-row sub-tiles */                                  \
        _Pragma("unroll")                                                       \
        for (int sub = 0; sub < 4; ++sub) {                                     \
            const int arow = sub * 16 + l15;                                    \
            const char* xr = (const char*)(&x_lds[buf][0]) + arow * 256;        \
            const char* hr = (const char*)(&h_lds[buf][0]) + arow * 256;        \
            const int aswz = (arow & 7) << 4;                                   \
            bf16x8 ax[4], ah[4];                                                \
            _Pragma("unroll")                                                   \
            for (int ks = 0; ks < 4; ++ks) {                                    \
                const int cb = (ks * 64 + khalf * 16) ^ aswz;                   \
                ax[ks] = *(const bf16x8*)(xr + cb);                             \
                ah[ks] = *(const bf16x8*)(hr + cb);                             \
            }                                                                   \
            f32x4 a_r  = {br,  br,  br,  br};                                   \
            f32x4 a_z  = {bz,  bz,  bz,  bz};                                   \
            f32x4 a_in = {bin, bin, bin, bin};                                  \
            f32x4 a_hn = {bhn, bhn, bhn, bhn};                                  \
            _Pragma("unroll")                                                   \
            for (int ks = 0; ks < 4; ++ks) {                                    \
                a_r  = __builtin_amdgcn_mfma_f32_16x16x32_bf16(ax[ks], wf[0][ks], a_r,  0, 0, 0); \
                a_r  = __builtin_amdgcn_mfma_f32_16x16x32_bf16(ah[ks], wf[3][ks], a_r,  0, 0, 0); \
                a_z  = __builtin_amdgcn_mfma_f32_16x16x32_bf16(ax[ks], wf[1][ks], a_z,  0, 0, 0); \
                a_z  = __builtin_amdgcn_mfma_f32_16x16x32_bf16(ah[ks], wf[4][ks], a_z,  0, 0, 0); \
                a_in = __builtin_amdgcn_mfma_f32_16x16x32_bf16(ax[ks], wf[2][ks], a_in, 0, 0, 0); \
                a_hn = __builtin_amdgcn_mfma_f32_16x16x32_bf16(ah[ks], wf[5][ks], a_hn, 0, 0, 0); \
            }                                                                   \
            _Pragma("unroll")                                                   \
            for (int q = 0; q < 4; ++q) {                                       \
                const int rl = sub * 16 + khalf * 4 + q;                        \
                const int tr = (t) * TR + rl;                                   \
                float rg = sigmoid_f(a_r[q]);                                   \
                float zg = sigmoid_f(a_z[q]);                                   \
                float ng = tanh_f(a_in[q] + rg * a_hn[q]);                      \
                unsigned short hu = *(const unsigned short*)(                   \
                    (const char*)(&h_lds[buf][0]) + rl * 256 + ((jcol * 2) ^ ((rl & 7) << 4))); \
                float h = bf2f(hu);                                             \
                float hnew = fmaf(zg, h - ng, ng);                              \
                int v = s_nid[tr];                                              \
                if (v & WINBIT)                                                 \
                    out_mem[(size_t)(v & (WINBIT - 1)) * DD + jcol] = hnew;     \
            }                                                                   \
        }                                                                       \
    }

#pragma unroll 1
    for (int tp = 0; tp < NT; tp += 2) {
        BODY(tp,     hP0, hP1, hP2, hP3, hQ0, hQ1, hQ2, hQ3);
        BODY(tp + 1, hQ0, hQ1, hQ2, hQ3, hP0, hP1, hP2, hP3);
    }
#undef BODY
#undef GLOADX
#undef GLOADH
}

// ---------------------------------------------------------------------------
extern "C" void kernel_launch(void* const* d_in, const int* in_sizes, int n_in,
                              void* d_out, int out_size, void* d_ws, size_t ws_size,
                              hipStream_t stream) {
    const float* memory      = (const float*)d_in[0];
    const float* last_update = (const float*)d_in[1];
    const float* messages    = (const float*)d_in[2];
    const float* timestamps  = (const float*)d_in[3];
    const float* W_ih        = (const float*)d_in[4];
    const float* W_hh        = (const float*)d_in[5];
    const float* b_ih        = (const float*)d_in[6];
    const float* b_hh        = (const float*)d_in[7];
    const int*   node_ids    = (const int*)d_in[8];

    float* out_mem = (float*)d_out;
    float* out_lu  = out_mem + (size_t)NN * DD;

    int* winner = (int*)d_ws;

    k_init<<<(NN / 4 + 255) / 256, 256, 0, stream>>>((int4*)winner);
    k_winner<<<BT / 256, 256, 0, stream>>>(node_ids, winner);
    k_copy<<<4096, 256, 0, stream>>>((const float4*)memory, last_update, timestamps,
                                     winner, (float4*)out_mem, out_lu);
    k_gru<<<GRUB, 512, 0, stream>>>(memory, messages, W_ih, W_hh, b_ih, b_hh,
                                    node_ids, winner, out_mem);
}